// Round 8
// baseline (1100.637 us; speedup 1.0000x reference)
//
#include <hip/hip_runtime.h>
#include <hip/hip_bf16.h>

namespace {

constexpr int NV = 32000;
constexpr int NE = 256;
constexpr int NH = 512;
constexpr int NB = 32;
constexpr int NT = 64;
constexpr int NG = 3 * NH;    // 1536
constexpr int NM = NB * NT;   // 2048
constexpr int SOS = 1;

typedef _Float16 f16_t;
typedef _Float16 f16x8 __attribute__((ext_vector_type(8)));
typedef _Float16 f16x2 __attribute__((ext_vector_type(2)));
typedef float f32x4 __attribute__((ext_vector_type(4)));

typedef __attribute__((address_space(1))) void gvoid_t;
typedef __attribute__((address_space(3))) void lvoid_t;

union P8 { f16_t h[4]; unsigned long long u; };
union P4 { f16_t h[2]; unsigned int u; };

// fragment-order offset of h[u][b] inside a 512x32 f16 step buffer.
// B-frag of mfma_f32_16x16x32_f16: lane l holds col n=l&15, k=(l>>4)*8+j.
__device__ __forceinline__ int fragoff(int u, int b) {
  return ((b >> 4) * 16 + (u >> 5)) * 512 +
         ((((u >> 3) & 3) * 16) + (b & 15)) * 8 + (u & 7);
}

__device__ __forceinline__ void load_wf(const float* wrow, f16x8* wf) {
  #pragma unroll
  for (int kc = 0; kc < 16; ++kc) {
    f32x4 a = *(const f32x4*)(wrow + kc * 32);
    f32x4 c = *(const f32x4*)(wrow + kc * 32 + 4);
    f16x8 w;
    w[0] = (f16_t)a[0]; w[1] = (f16_t)a[1]; w[2] = (f16_t)a[2]; w[3] = (f16_t)a[3];
    w[4] = (f16_t)c[0]; w[5] = (f16_t)c[1]; w[6] = (f16_t)c[2]; w[7] = (f16_t)c[3];
    wf[kc] = w;
  }
}

__device__ __forceinline__ float sigm(float x) { return 1.f / (1.f + __expf(-x)); }

// Per-block flag words, each on its own 64B line (int stride 16).
__device__ __forceinline__ void wait_flag(int* p, int target) {
  while (__hip_atomic_load(p, __ATOMIC_RELAXED, __HIP_MEMORY_SCOPE_AGENT) < target)
    __builtin_amdgcn_s_sleep(1);
}

// Write-through 8B/4B stores (relaxed agent atomics) — data lands at the
// coherent point; paired with COHERENT LOADS below, no acquire fence needed.
__device__ __forceinline__ void store8(void* dst, unsigned long long v) {
  __hip_atomic_store((unsigned long long*)dst, v, __ATOMIC_RELAXED,
                     __HIP_MEMORY_SCOPE_AGENT);
}
__device__ __forceinline__ void store4(void* dst, unsigned int v) {
  __hip_atomic_store((unsigned int*)dst, v, __ATOMIC_RELAXED,
                     __HIP_MEMORY_SCOPE_AGENT);
}

// Coherent 16B load as 2x8B relaxed agent atomics — reads the coherent point,
// immune to stale L1/L2 lines. This is what lets us DELETE the per-step
// acquire fence (buffer_inv L2 walk), the R3-R7 constant-cost suspect.
__device__ __forceinline__ f16x8 cload16(const f16_t* p) {
  union { unsigned long long u[2]; f16x8 v; } r;
  r.u[0] = __hip_atomic_load((const unsigned long long*)p, __ATOMIC_RELAXED,
                             __HIP_MEMORY_SCOPE_AGENT);
  r.u[1] = __hip_atomic_load((const unsigned long long*)p + 1, __ATOMIC_RELAXED,
                             __HIP_MEMORY_SCOPE_AGENT);
  return r.v;
}

// ---------------- prologue kernels ----------------

__global__ __launch_bounds__(256) void k_hinit(const float* __restrict__ eh,
                                               f16_t* __restrict__ hb0,
                                               f16_t* __restrict__ hb1) {
  int idx = blockIdx.x * 256 + threadIdx.x;   // l*16384 + b*512 + u
  int u = idx & 511;
  int b = (idx >> 9) & 31;
  int l = idx >> 14;
  f16_t v = (f16_t)eh[idx];
  (l ? hb1 : hb0)[fragoff(u, b)] = v;
}

__global__ __launch_bounds__(256) void k_wcvt(const float* __restrict__ w,
                                              f16_t* __restrict__ wb) {
  int idx = blockIdx.x * 256 + threadIdx.x;   // < NV*NH/4
  f32x4 v = ((const f32x4*)w)[idx];
  f16x2 o0, o1;
  o0[0] = (f16_t)v[0]; o0[1] = (f16_t)v[1];
  o1[0] = (f16_t)v[2]; o1[1] = (f16_t)v[3];
  ((f16x2*)wb)[2 * idx] = o0;
  ((f16x2*)wb)[2 * idx + 1] = o1;
}

__global__ __launch_bounds__(256) void k_gi0(const int* __restrict__ tgt,
                                             const float* __restrict__ emb,
                                             const float* __restrict__ Wih0,
                                             const float* __restrict__ bih0,
                                             f16_t* __restrict__ Gi0) {
  __shared__ float xs[NE * NB];   // [e][b]
  __shared__ int toks[NB];
  const int t = blockIdx.y;
  const int tid = threadIdx.x;
  if (tid < NB) toks[tid] = (t == 0) ? SOS : tgt[tid * NT + (t - 1)];
  __syncthreads();
  {
    const int b = tid >> 3, e0 = (tid & 7) * 32;
    const float* er = emb + (size_t)toks[b] * NE + e0;
    #pragma unroll 8
    for (int i = 0; i < 32; ++i) {
      float v = er[i];
      xs[(e0 + i) * NB + b] = v > 0.f ? v : 0.f;
    }
  }
  __syncthreads();
  const int b = tid & 31;
  #pragma unroll
  for (int jj = 0; jj < 8; ++jj) {
    const int j = blockIdx.x * 64 + jj * 8 + (tid >> 5);
    float acc = bih0[j];
    const f32x4* wr = (const f32x4*)(Wih0 + (size_t)j * NE);
    #pragma unroll 4
    for (int e4 = 0; e4 < NE / 4; ++e4) {
      f32x4 w = wr[e4];
      acc += w[0] * xs[(4 * e4 + 0) * NB + b] + w[1] * xs[(4 * e4 + 1) * NB + b]
           + w[2] * xs[(4 * e4 + 2) * NB + b] + w[3] * xs[(4 * e4 + 3) * NB + b];
    }
    Gi0[((size_t)t * NG + j) * NB + b] = (f16_t)acc;
  }
}

// ---------------- persistent MFMA recurrence ----------------
// blocks 0..7: layer 0 (64 units each).  blocks 8..23: layer 1 (32 units each).
// h passed via per-step frag-order f16 buffers hb0[t], hb1[t] (t=0 is initial).
// R8: fence-free protocol — WT atomic stores + coherent atomic loads; flags as
// before. Direct frag-order h stores (consecutive-unit thread mapping) delete
// the hstage/astage LDS staging and one barrier per step.

__global__ __launch_bounds__(768) void k_rnn2(
    const f16_t* __restrict__ Gi0,
    const float* __restrict__ Whh0, const float* __restrict__ bhh0,
    const float* __restrict__ Wih1, const float* __restrict__ bih1,
    const float* __restrict__ Whh1, const float* __restrict__ bhh1,
    const float* __restrict__ eh,
    f16_t* __restrict__ hb0, f16_t* __restrict__ hb1,
    f16_t* __restrict__ Abf, float* __restrict__ hfin,
    int* f0, int* f1) {
  __shared__ __align__(16) float gLDS[6144];      // 24 KB
  const int tid = threadIdx.x;
  const int wave = tid >> 6, lane = tid & 63;
  const int bid = blockIdx.x;
  const int eb = tid & 31;

  if (bid < 8) {
    // ---------------- layer 0 ----------------
    const int ug = bid * 64;
    const int gate = wave >> 2, tile = wave & 3;
    const int row = gate * 512 + ug + tile * 16 + (lane & 15);
    f16x8 wf[16];
    load_wf(Whh0 + (size_t)row * NH + (lane >> 4) * 8, wf);

    const int eu = (tid >> 5) * 4;          // tid<512: units ug+eu .. ug+eu+3
    float hprev[4], br[4], bz[4], bn[4];
    if (tid < 512) {
      #pragma unroll
      for (int i = 0; i < 4; ++i) {
        int u = ug + eu + i;
        hprev[i] = eh[eb * NH + u];
        br[i] = bhh0[u]; bz[i] = bhh0[512 + u]; bn[i] = bhh0[1024 + u];
      }
    }

    for (int t = 0; t < NT; ++t) {
      float gr[4], gz[4], gn[4];
      if (tid < 512) {                       // prefetch gi (overlaps the wait)
        const f16_t* g = Gi0 + (size_t)t * NG * NB;
        #pragma unroll
        for (int i = 0; i < 4; ++i) {
          int u = ug + eu + i;
          gr[i] = (float)g[u * NB + eb];
          gz[i] = (float)g[(512 + u) * NB + eb];
          gn[i] = (float)g[(1024 + u) * NB + eb];
        }
      }
      if (t > 0 && tid < 8) wait_flag(f0 + tid * 16, t);
      asm volatile("" ::: "memory");
      __syncthreads();
      const f16_t* hb = hb0 + (size_t)t * 16384;
      f32x4 acc0 = {0.f, 0.f, 0.f, 0.f}, acc1 = {0.f, 0.f, 0.f, 0.f};
      #pragma unroll
      for (int kc = 0; kc < 16; ++kc) {
        f16x8 b0 = cload16(hb + kc * 512 + lane * 8);
        f16x8 b1 = cload16(hb + (16 + kc) * 512 + lane * 8);
        acc0 = __builtin_amdgcn_mfma_f32_16x16x32_f16(wf[kc], b0, acc0, 0, 0, 0);
        acc1 = __builtin_amdgcn_mfma_f32_16x16x32_f16(wf[kc], b1, acc1, 0, 0, 0);
      }
      {
        const int m0 = (lane >> 4) * 4, col = lane & 15;
        #pragma unroll
        for (int r = 0; r < 4; ++r) {
          int ul = tile * 16 + m0 + r;
          gLDS[(gate * 64 + ul) * 32 + col] = acc0[r];
          gLDS[(gate * 64 + ul) * 32 + 16 + col] = acc1[r];
        }
      }
      __syncthreads();
      if (tid < 512) {
        P8 p;
        #pragma unroll
        for (int i = 0; i < 4; ++i) {
          int ul = eu + i;
          float rt = gLDS[(0 * 64 + ul) * 32 + eb];
          float zt = gLDS[(1 * 64 + ul) * 32 + eb];
          float nt_ = gLDS[(2 * 64 + ul) * 32 + eb];
          float r = sigm(gr[i] + rt + br[i]);
          float z = sigm(gz[i] + zt + bz[i]);
          float n = tanhf(gn[i] + r * (nt_ + bn[i]));
          float hnew = (1.f - z) * n + z * hprev[i];
          hprev[i] = hnew;
          p.h[i] = (f16_t)hnew;
          if (t == NT - 1) hfin[eb * NH + ug + ul] = hnew;
        }
        store8(hb0 + (size_t)(t + 1) * 16384 + fragoff(ug + eu, eb), p.u);
      }
      __syncthreads();
      if (tid == 0)
        __hip_atomic_store(f0 + bid * 16, t + 1, __ATOMIC_RELEASE,
                           __HIP_MEMORY_SCOPE_AGENT);
    }
  } else {
    // ---------------- layer 1 ----------------
    const int g = bid - 8, ug = g * 32;
    const int mm = wave >= 6;                 // 0: Wih1 (x=h0), 1: Whh1 (h1)
    const int w6 = mm ? wave - 6 : wave;
    const int gate = w6 >> 1, tile = w6 & 1;
    const int row = gate * 512 + ug + tile * 16 + (lane & 15);
    const float* W = mm ? Whh1 : Wih1;
    f16x8 wf[16];
    load_wf(W + (size_t)row * NH + (lane >> 4) * 8, wf);

    const int eu = (tid >> 5) * 2;          // tid<512: units ug+eu, ug+eu+1
    float hprev[2], bir[2], biz[2], bin_[2], bhr[2], bhz[2], bhn[2];
    if (tid < 512) {
      #pragma unroll
      for (int i = 0; i < 2; ++i) {
        int u = ug + eu + i;
        hprev[i] = eh[16384 + eb * NH + u];
        bir[i] = bih1[u]; biz[i] = bih1[512 + u]; bin_[i] = bih1[1024 + u];
        bhr[i] = bhh1[u]; bhz[i] = bhh1[512 + u]; bhn[i] = bhh1[1024 + u];
      }
    }

    for (int t = 0; t < NT; ++t) {
      if (tid < 24) {                        // parallel poll: 8x f0, 16x f1
        int* p   = (tid < 8) ? (f0 + tid * 16) : (f1 + (tid - 8) * 16);
        int tgt  = (tid < 8) ? (t + 1) : t;
        wait_flag(p, tgt);
      }
      asm volatile("" ::: "memory");
      __syncthreads();
      const f16_t* hb = mm ? (hb1 + (size_t)t * 16384)
                           : (hb0 + (size_t)(t + 1) * 16384);
      f32x4 acc0 = {0.f, 0.f, 0.f, 0.f}, acc1 = {0.f, 0.f, 0.f, 0.f};
      #pragma unroll
      for (int kc = 0; kc < 16; ++kc) {
        f16x8 b0 = cload16(hb + kc * 512 + lane * 8);
        f16x8 b1 = cload16(hb + (16 + kc) * 512 + lane * 8);
        acc0 = __builtin_amdgcn_mfma_f32_16x16x32_f16(wf[kc], b0, acc0, 0, 0, 0);
        acc1 = __builtin_amdgcn_mfma_f32_16x16x32_f16(wf[kc], b1, acc1, 0, 0, 0);
      }
      {
        const int m0 = (lane >> 4) * 4, col = lane & 15;
        #pragma unroll
        for (int r = 0; r < 4; ++r) {
          int ul = tile * 16 + m0 + r;
          gLDS[((mm * 3 + gate) * 32 + ul) * 32 + col] = acc0[r];
          gLDS[((mm * 3 + gate) * 32 + ul) * 32 + 16 + col] = acc1[r];
        }
      }
      __syncthreads();
      if (tid < 512) {
        P4 p;
        #pragma unroll
        for (int i = 0; i < 2; ++i) {
          int ul = eu + i;
          float ir  = gLDS[((0 * 3 + 0) * 32 + ul) * 32 + eb] + bir[i];
          float iz  = gLDS[((0 * 3 + 1) * 32 + ul) * 32 + eb] + biz[i];
          float in_ = gLDS[((0 * 3 + 2) * 32 + ul) * 32 + eb] + bin_[i];
          float hr  = gLDS[((1 * 3 + 0) * 32 + ul) * 32 + eb] + bhr[i];
          float hz  = gLDS[((1 * 3 + 1) * 32 + ul) * 32 + eb] + bhz[i];
          float hn  = gLDS[((1 * 3 + 2) * 32 + ul) * 32 + eb] + bhn[i];
          float r = sigm(ir + hr);
          float z = sigm(iz + hz);
          float n = tanhf(in_ + r * hn);
          float hnew = (1.f - z) * n + z * hprev[i];
          hprev[i] = hnew;
          p.h[i] = (f16_t)hnew;
          if (t == NT - 1) hfin[16384 + eb * NH + ug + ul] = hnew;
        }
        store4(hb1 + (size_t)(t + 1) * 16384 + fragoff(ug + eu, eb), p.u);
        store4(Abf + ((size_t)(eb * 64 + t)) * 512 + ug + eu, p.u);
      }
      __syncthreads();
      if (tid == 0)
        __hip_atomic_store(f1 + g * 16, t + 1, __ATOMIC_RELEASE,
                           __HIP_MEMORY_SCOPE_AGENT);
    }
  }
}

// ---------------- output projection (f16 MFMA, m97-style) ----------------
// R8: grid is (m-panels, n-tiles) so the 16 co-dispatched m-panels of one
// n-tile share the B(W_out) tile via L2 instead of 16 full 32MB B sweeps.

__global__ __launch_bounds__(256) void k_gemm(const f16_t* __restrict__ A,
                                              const f16_t* __restrict__ Bw,
                                              const float* __restrict__ bout,
                                              float* __restrict__ C) {
  __shared__ __align__(16) f16_t As[2][128 * 32];
  __shared__ __align__(16) f16_t Bs[2][128 * 32];
  const int m0 = blockIdx.x * 128;
  const int n0 = blockIdx.y * 128;
  const int tid = threadIdx.x;
  const int wave = tid >> 6;
  const int lane = tid & 63;
  const int r_in = lane >> 2;
  const int c8 = (lane & 3) * 8;

  const f16_t* Ag = A  + (size_t)(m0 + wave * 32 + r_in) * NH + c8;
  const f16_t* Bg = Bw + (size_t)(n0 + wave * 32 + r_in) * NH + c8;

  auto stage = [&](int buf, int kk) {
    f16_t* la = &As[buf][(wave * 32) * 32];
    f16_t* lb = &Bs[buf][(wave * 32) * 32];
    __builtin_amdgcn_global_load_lds((gvoid_t*)(Ag + kk),            (lvoid_t*)la,             16, 0, 0);
    __builtin_amdgcn_global_load_lds((gvoid_t*)(Ag + kk + 16 * NH),  (lvoid_t*)(la + 16 * 32), 16, 0, 0);
    __builtin_amdgcn_global_load_lds((gvoid_t*)(Bg + kk),            (lvoid_t*)lb,             16, 0, 0);
    __builtin_amdgcn_global_load_lds((gvoid_t*)(Bg + kk + 16 * NH),  (lvoid_t*)(lb + 16 * 32), 16, 0, 0);
  };

  f32x4 acc[4][4];
  #pragma unroll
  for (int i = 0; i < 4; ++i)
    #pragma unroll
    for (int j = 0; j < 4; ++j)
      acc[i][j] = (f32x4){0.f, 0.f, 0.f, 0.f};

  const int wm = (wave >> 1) * 64;
  const int wn = (wave & 1) * 64;
  const int arow = lane & 15;
  const int kg = (lane >> 4) * 8;

  stage(0, 0);
  __syncthreads();
  for (int kt = 0; kt < NH / 32; ++kt) {
    const int buf = kt & 1;
    if (kt + 1 < NH / 32) stage(buf ^ 1, (kt + 1) * 32);
    f16x8 af[4], bfr[4];
    #pragma unroll
    for (int i = 0; i < 4; ++i) {
      af[i]  = *(const f16x8*)&As[buf][(wm + i * 16 + arow) * 32 + kg];
      bfr[i] = *(const f16x8*)&Bs[buf][(wn + i * 16 + arow) * 32 + kg];
    }
    #pragma unroll
    for (int i = 0; i < 4; ++i)
      #pragma unroll
      for (int j = 0; j < 4; ++j)
        acc[i][j] = __builtin_amdgcn_mfma_f32_16x16x32_f16(af[i], bfr[j], acc[i][j], 0, 0, 0);
    __syncthreads();
  }

  const int crow = (lane >> 4) * 4;
  const int ccol = lane & 15;
  #pragma unroll
  for (int j = 0; j < 4; ++j) {
    const int gcol = n0 + wn + j * 16 + ccol;
    const float bb = bout[gcol];
    #pragma unroll
    for (int i = 0; i < 4; ++i) {
      const int grow = m0 + wm + i * 16 + crow;
      #pragma unroll
      for (int r = 0; r < 4; ++r)
        C[(size_t)(grow + r) * NV + gcol] = acc[i][j][r] + bb;
    }
  }
}

// ---------------- in-place row log_softmax ----------------

__global__ __launch_bounds__(256) void k_lsm(float* __restrict__ out) {
  __shared__ f16_t row[NV];
  __shared__ float redm[4], reds[4];
  const int m = blockIdx.x;
  float* p = out + (size_t)m * NV;
  const int tid = threadIdx.x;
  float mx = -3.0e38f;
  for (int i = tid; i < NV; i += 256) {
    float x = p[i];
    row[i] = (f16_t)x;
    mx = fmaxf(mx, x);
  }
  #pragma unroll
  for (int o = 1; o < 64; o <<= 1) mx = fmaxf(mx, __shfl_xor(mx, o, 64));
  if ((tid & 63) == 0) redm[tid >> 6] = mx;
  __syncthreads();
  mx = fmaxf(fmaxf(redm[0], redm[1]), fmaxf(redm[2], redm[3]));
  float s = 0.f;
  for (int i = tid; i < NV; i += 256) s += __expf((float)row[i] - mx);
  #pragma unroll
  for (int o = 1; o < 64; o <<= 1) s += __shfl_xor(s, o, 64);
  if ((tid & 63) == 0) reds[tid >> 6] = s;
  __syncthreads();
  const float lse = mx + __logf(reds[0] + reds[1] + reds[2] + reds[3]);
  for (int i = tid; i < NV; i += 256) p[i] = (float)row[i] - lse;
}

// ws layout (bytes)
constexpr size_t WS_F0  = 0;      // 8 flags, 64B apart
constexpr size_t WS_F1  = 512;    // 16 flags, 64B apart
constexpr size_t WS_GI0 = 2048;
constexpr size_t WS_HB0 = WS_GI0 + sizeof(f16_t) * (size_t)NT * NG * NB;       // 6.29 MB
constexpr size_t WS_HB1 = WS_HB0 + sizeof(f16_t) * (size_t)(NT + 1) * NH * NB; // +2.13 MB
constexpr size_t WS_ABF = WS_HB1 + sizeof(f16_t) * (size_t)(NT + 1) * NH * NB;
constexpr size_t WS_WF  = WS_ABF + sizeof(f16_t) * (size_t)NM * NH;

}  // namespace

extern "C" void kernel_launch(void* const* d_in, const int* in_sizes, int n_in,
                              void* d_out, int out_size, void* d_ws, size_t ws_size,
                              hipStream_t stream) {
  const float* enc_h = (const float*)d_in[1];
  const int*   tgt   = (const int*)d_in[2];
  const float* emb   = (const float*)d_in[3];
  const float* Wih0  = (const float*)d_in[4];
  const float* Whh0  = (const float*)d_in[5];
  const float* bih0  = (const float*)d_in[6];
  const float* bhh0  = (const float*)d_in[7];
  const float* Wih1  = (const float*)d_in[8];
  const float* Whh1  = (const float*)d_in[9];
  const float* bih1  = (const float*)d_in[10];
  const float* bhh1  = (const float*)d_in[11];
  const float* Wout  = (const float*)d_in[12];
  const float* bout  = (const float*)d_in[13];

  char* ws = (char*)d_ws;
  int*    f0   = (int*)(ws + WS_F0);
  int*    f1   = (int*)(ws + WS_F1);
  f16_t*  Gi0  = (f16_t*)(ws + WS_GI0);
  f16_t*  hb0  = (f16_t*)(ws + WS_HB0);
  f16_t*  hb1  = (f16_t*)(ws + WS_HB1);
  f16_t*  Abf  = (f16_t*)(ws + WS_ABF);
  f16_t*  Wf   = (f16_t*)(ws + WS_WF);

  float* out  = (float*)d_out;
  float* hfin = out + (size_t)NM * NV;

  hipMemsetAsync(ws, 0, 2048, stream);
  k_hinit<<<(2 * NB * NH) / 256, 256, 0, stream>>>(enc_h, hb0, hb1);
  k_gi0<<<dim3(NG / 64, NT), 256, 0, stream>>>(tgt, emb, Wih0, bih0, Gi0);
  k_rnn2<<<24, 768, 0, stream>>>(Gi0, Whh0, bhh0, Wih1, bih1, Whh1, bhh1,
                                 enc_h, hb0, hb1, Abf, hfin, f0, f1);
  k_wcvt<<<(NV * NH / 4) / 256, 256, 0, stream>>>(Wout, Wf);
  k_gemm<<<dim3(NM / 128, NV / 128), 256, 0, stream>>>(Abf, Wf, bout, out);
  k_lsm<<<NM, 256, 0, stream>>>(out);
}

// Round 9
// 976.960 us; speedup vs baseline: 1.1266x; 1.1266x over previous
//
#include <hip/hip_runtime.h>
#include <hip/hip_bf16.h>

namespace {

constexpr int NV = 32000;
constexpr int NE = 256;
constexpr int NH = 512;
constexpr int NB = 32;
constexpr int NT = 64;
constexpr int NG = 3 * NH;    // 1536
constexpr int NM = NB * NT;   // 2048
constexpr int SOS = 1;

typedef _Float16 f16_t;
typedef _Float16 f16x8 __attribute__((ext_vector_type(8)));
typedef _Float16 f16x2 __attribute__((ext_vector_type(2)));
typedef float f32x4 __attribute__((ext_vector_type(4)));

typedef __attribute__((address_space(1))) void gvoid_t;
typedef __attribute__((address_space(3))) void lvoid_t;

// fragment-order offset of h[u][b] inside a 512x32 f16 step buffer.
// B-frag of mfma_f32_16x16x32_f16: lane l holds col n=l&15, k=(l>>4)*8+j.
__device__ __forceinline__ int fragoff(int u, int b) {
  return ((b >> 4) * 16 + (u >> 5)) * 512 +
         ((((u >> 3) & 3) * 16) + (b & 15)) * 8 + (u & 7);
}

__device__ __forceinline__ void load_wf(const float* wrow, f16x8* wf) {
  #pragma unroll
  for (int kc = 0; kc < 16; ++kc) {
    f32x4 a = *(const f32x4*)(wrow + kc * 32);
    f32x4 c = *(const f32x4*)(wrow + kc * 32 + 4);
    f16x8 w;
    w[0] = (f16_t)a[0]; w[1] = (f16_t)a[1]; w[2] = (f16_t)a[2]; w[3] = (f16_t)a[3];
    w[4] = (f16_t)c[0]; w[5] = (f16_t)c[1]; w[6] = (f16_t)c[2]; w[7] = (f16_t)c[3];
    wf[kc] = w;
  }
}

__device__ __forceinline__ float sigm(float x) { return 1.f / (1.f + __expf(-x)); }

// Per-block flag words, each on its own 64B line (int stride 16).
__device__ __forceinline__ void wait_flag(int* p, int target) {
  while (__hip_atomic_load(p, __ATOMIC_RELAXED, __HIP_MEMORY_SCOPE_AGENT) < target)
    __builtin_amdgcn_s_sleep(1);
}

// Write-through 8B store (relaxed agent atomic): data visible at coherent point.
__device__ __forceinline__ void store8(void* dst, unsigned long long v) {
  __hip_atomic_store((unsigned long long*)dst, v, __ATOMIC_RELAXED,
                     __HIP_MEMORY_SCOPE_AGENT);
}

// ---------------- prologue kernels ----------------

__global__ __launch_bounds__(256) void k_hinit(const float* __restrict__ eh,
                                               f16_t* __restrict__ hb0,
                                               f16_t* __restrict__ hb1) {
  int idx = blockIdx.x * 256 + threadIdx.x;   // l*16384 + b*512 + u
  int u = idx & 511;
  int b = (idx >> 9) & 31;
  int l = idx >> 14;
  f16_t v = (f16_t)eh[idx];
  (l ? hb1 : hb0)[fragoff(u, b)] = v;
}

__global__ __launch_bounds__(256) void k_gi0(const int* __restrict__ tgt,
                                             const float* __restrict__ emb,
                                             const float* __restrict__ Wih0,
                                             const float* __restrict__ bih0,
                                             f16_t* __restrict__ Gi0) {
  __shared__ float xs[NE * NB];   // [e][b]
  __shared__ int toks[NB];
  const int t = blockIdx.y;
  const int tid = threadIdx.x;
  if (tid < NB) toks[tid] = (t == 0) ? SOS : tgt[tid * NT + (t - 1)];
  __syncthreads();
  {
    const int b = tid >> 3, e0 = (tid & 7) * 32;
    const float* er = emb + (size_t)toks[b] * NE + e0;
    #pragma unroll 8
    for (int i = 0; i < 32; ++i) {
      float v = er[i];
      xs[(e0 + i) * NB + b] = v > 0.f ? v : 0.f;
    }
  }
  __syncthreads();
  const int b = tid & 31;
  #pragma unroll
  for (int jj = 0; jj < 8; ++jj) {
    const int j = blockIdx.x * 64 + jj * 8 + (tid >> 5);
    float acc = bih0[j];
    const f32x4* wr = (const f32x4*)(Wih0 + (size_t)j * NE);
    #pragma unroll 4
    for (int e4 = 0; e4 < NE / 4; ++e4) {
      f32x4 w = wr[e4];
      acc += w[0] * xs[(4 * e4 + 0) * NB + b] + w[1] * xs[(4 * e4 + 1) * NB + b]
           + w[2] * xs[(4 * e4 + 2) * NB + b] + w[3] * xs[(4 * e4 + 3) * NB + b];
    }
    Gi0[((size_t)t * NG + j) * NB + b] = (f16_t)acc;
  }
}

// ---------------- mega kernel: persistent rnn + overlapped gemm ----------------
// grid = 256 blocks x 768 threads — ALL co-resident (1 block/CU) -> no deadlock.
// blocks 0..7:   layer 0 (R7-proven code), 64 units each.
// blocks 8..23:  layer 1 (R7-proven code), 32 units each; Abf row m = t*32+b.
// blocks 24..255: output-projection gemm, one 128-col n-tile each (18 do two);
//   per tile: convert own W_out slab fp32->f16, then 8 m-panels of 256 rows,
//   each gated on f1 flags (t-progress) -> gemm runs DURING the recurrence.

__global__ __launch_bounds__(768) void k_mega(
    const f16_t* __restrict__ Gi0,
    const float* __restrict__ Whh0, const float* __restrict__ bhh0,
    const float* __restrict__ Wih1, const float* __restrict__ bih1,
    const float* __restrict__ Whh1, const float* __restrict__ bhh1,
    const float* __restrict__ eh,
    f16_t* __restrict__ hb0, f16_t* __restrict__ hb1,
    f16_t* __restrict__ Abf, float* __restrict__ hfin,
    const float* __restrict__ Wout, const float* __restrict__ bout,
    f16_t* __restrict__ Wf, float* __restrict__ C,
    int* f0, int* f1) {
  __shared__ __align__(16) char pool[49152];   // rnn: 30KB | gemm: 48KB
  const int tid = threadIdx.x;
  const int wave = tid >> 6, lane = tid & 63;
  const int bid = blockIdx.x;
  const int eb = tid & 31, eu0 = (tid >> 5) & 15;

  if (bid < 8) {
    // ---------------- layer 0 (R7 verbatim) ----------------
    float* gLDS = (float*)pool;                       // 24 KB
    f16_t* hstage = (f16_t*)(pool + 24576);           // 4 KB
    const int ug = bid * 64;
    const int gate = wave >> 2, tile = wave & 3;
    const int row = gate * 512 + ug + tile * 16 + (lane & 15);
    f16x8 wf[16];
    load_wf(Whh0 + (size_t)row * NH + (lane >> 4) * 8, wf);

    float hprev[4], br[4], bz[4], bn[4];
    if (tid < 512) {
      #pragma unroll
      for (int i = 0; i < 4; ++i) {
        int u = ug + eu0 + i * 16;
        hprev[i] = eh[eb * NH + u];
        br[i] = bhh0[u]; bz[i] = bhh0[512 + u]; bn[i] = bhh0[1024 + u];
      }
    }

    for (int t = 0; t < NT; ++t) {
      float gr[4], gz[4], gn[4];
      if (tid < 512) {                       // prefetch gi (overlaps the wait)
        const f16_t* g = Gi0 + (size_t)t * NG * NB;
        #pragma unroll
        for (int i = 0; i < 4; ++i) {
          int u = ug + eu0 + i * 16;
          gr[i] = (float)g[u * NB + eb];
          gz[i] = (float)g[(512 + u) * NB + eb];
          gn[i] = (float)g[(1024 + u) * NB + eb];
        }
      }
      if (t > 0) {
        if (tid < 8) wait_flag(f0 + tid * 16, t);
        if (tid == 0) __builtin_amdgcn_fence(__ATOMIC_ACQUIRE, "agent");
      }
      __syncthreads();
      const f16_t* hb = hb0 + (size_t)t * 16384;
      f32x4 acc0 = {0.f, 0.f, 0.f, 0.f}, acc1 = {0.f, 0.f, 0.f, 0.f};
      #pragma unroll
      for (int kc = 0; kc < 16; ++kc) {
        f16x8 b0 = *(const f16x8*)(hb + kc * 512 + lane * 8);
        f16x8 b1 = *(const f16x8*)(hb + (16 + kc) * 512 + lane * 8);
        acc0 = __builtin_amdgcn_mfma_f32_16x16x32_f16(wf[kc], b0, acc0, 0, 0, 0);
        acc1 = __builtin_amdgcn_mfma_f32_16x16x32_f16(wf[kc], b1, acc1, 0, 0, 0);
      }
      {
        const int m0 = (lane >> 4) * 4, col = lane & 15;
        #pragma unroll
        for (int r = 0; r < 4; ++r) {
          int ul = tile * 16 + m0 + r;
          gLDS[(gate * 64 + ul) * 32 + col] = acc0[r];
          gLDS[(gate * 64 + ul) * 32 + 16 + col] = acc1[r];
        }
      }
      __syncthreads();
      if (tid < 512) {
        #pragma unroll
        for (int i = 0; i < 4; ++i) {
          int ul = eu0 + i * 16;
          float rt = gLDS[(0 * 64 + ul) * 32 + eb];
          float zt = gLDS[(1 * 64 + ul) * 32 + eb];
          float nt_ = gLDS[(2 * 64 + ul) * 32 + eb];
          float r = sigm(gr[i] + rt + br[i]);
          float z = sigm(gz[i] + zt + bz[i]);
          float n = tanhf(gn[i] + r * (nt_ + bn[i]));
          float hnew = (1.f - z) * n + z * hprev[i];
          hprev[i] = hnew;
          hstage[((eb >> 4) * 2 + (ul >> 5)) * 512 +
                 ((((ul >> 3) & 3) * 16) + (eb & 15)) * 8 + (ul & 7)] = (f16_t)hnew;
          if (t == NT - 1) hfin[eb * NH + ug + ul] = hnew;
        }
      }
      __syncthreads();
      if (tid < 512) {
        const int chunk = tid >> 7, w = tid & 127;
        const unsigned long long v =
            *(const unsigned long long*)(hstage + chunk * 512 + w * 4);
        store8(hb0 + (size_t)(t + 1) * 16384 +
               ((chunk >> 1) * 16 + (ug >> 5) + (chunk & 1)) * 512 + w * 4, v);
      }
      __syncthreads();
      if (tid == 0)
        __hip_atomic_store(f0 + bid * 16, t + 1, __ATOMIC_RELEASE,
                           __HIP_MEMORY_SCOPE_AGENT);
    }
  } else if (bid < 24) {
    // ---------------- layer 1 (R7 verbatim, Abf row = t*32+b) ----------------
    float* gLDS = (float*)pool;
    f16_t* hstage = (f16_t*)(pool + 24576);
    f16_t* astage = (f16_t*)(pool + 28672);
    const int g = bid - 8, ug = g * 32;
    const int mm = wave >= 6;                 // 0: Wih1 (x=h0), 1: Whh1 (h1)
    const int w6 = mm ? wave - 6 : wave;
    const int gate = w6 >> 1, tile = w6 & 1;
    const int row = gate * 512 + ug + tile * 16 + (lane & 15);
    const float* W = mm ? Whh1 : Wih1;
    f16x8 wf[16];
    load_wf(W + (size_t)row * NH + (lane >> 4) * 8, wf);

    float hprev[2], bir[2], biz[2], bin_[2], bhr[2], bhz[2], bhn[2];
    if (tid < 512) {
      #pragma unroll
      for (int i = 0; i < 2; ++i) {
        int u = ug + eu0 + i * 16;
        hprev[i] = eh[16384 + eb * NH + u];
        bir[i] = bih1[u]; biz[i] = bih1[512 + u]; bin_[i] = bih1[1024 + u];
        bhr[i] = bhh1[u]; bhz[i] = bhh1[512 + u]; bhn[i] = bhh1[1024 + u];
      }
    }

    for (int t = 0; t < NT; ++t) {
      if (tid < 24) {                        // parallel poll: 8x f0, 16x f1
        int* p   = (tid < 8) ? (f0 + tid * 16) : (f1 + (tid - 8) * 16);
        int tgt  = (tid < 8) ? (t + 1) : t;
        wait_flag(p, tgt);
      }
      if (tid == 0) __builtin_amdgcn_fence(__ATOMIC_ACQUIRE, "agent");
      __syncthreads();
      const f16_t* hb = mm ? (hb1 + (size_t)t * 16384)
                           : (hb0 + (size_t)(t + 1) * 16384);
      f32x4 acc0 = {0.f, 0.f, 0.f, 0.f}, acc1 = {0.f, 0.f, 0.f, 0.f};
      #pragma unroll
      for (int kc = 0; kc < 16; ++kc) {
        f16x8 b0 = *(const f16x8*)(hb + kc * 512 + lane * 8);
        f16x8 b1 = *(const f16x8*)(hb + (16 + kc) * 512 + lane * 8);
        acc0 = __builtin_amdgcn_mfma_f32_16x16x32_f16(wf[kc], b0, acc0, 0, 0, 0);
        acc1 = __builtin_amdgcn_mfma_f32_16x16x32_f16(wf[kc], b1, acc1, 0, 0, 0);
      }
      {
        const int m0 = (lane >> 4) * 4, col = lane & 15;
        #pragma unroll
        for (int r = 0; r < 4; ++r) {
          int ul = tile * 16 + m0 + r;
          gLDS[((mm * 3 + gate) * 32 + ul) * 32 + col] = acc0[r];
          gLDS[((mm * 3 + gate) * 32 + ul) * 32 + 16 + col] = acc1[r];
        }
      }
      __syncthreads();
      if (tid < 512) {
        #pragma unroll
        for (int i = 0; i < 2; ++i) {
          int ul = eu0 + i * 16;
          float ir  = gLDS[((0 * 3 + 0) * 32 + ul) * 32 + eb] + bir[i];
          float iz  = gLDS[((0 * 3 + 1) * 32 + ul) * 32 + eb] + biz[i];
          float in_ = gLDS[((0 * 3 + 2) * 32 + ul) * 32 + eb] + bin_[i];
          float hr  = gLDS[((1 * 3 + 0) * 32 + ul) * 32 + eb] + bhr[i];
          float hz  = gLDS[((1 * 3 + 1) * 32 + ul) * 32 + eb] + bhz[i];
          float hn  = gLDS[((1 * 3 + 2) * 32 + ul) * 32 + eb] + bhn[i];
          float r = sigm(ir + hr);
          float z = sigm(iz + hz);
          float n = tanhf(in_ + r * hn);
          float hnew = (1.f - z) * n + z * hprev[i];
          hprev[i] = hnew;
          f16_t hv = (f16_t)hnew;
          hstage[(eb >> 4) * 512 +
                 ((((ul >> 3) & 3) * 16) + (eb & 15)) * 8 + (ul & 7)] = hv;
          astage[eb * 32 + ul] = hv;
          if (t == NT - 1) hfin[16384 + eb * NH + ug + ul] = hnew;
        }
      }
      __syncthreads();
      if (tid < 256) {
        const int chunk = tid >> 7, w = tid & 127;
        const unsigned long long v =
            *(const unsigned long long*)(hstage + chunk * 512 + w * 4);
        store8(hb1 + (size_t)(t + 1) * 16384 + (chunk * 16 + g) * 512 + w * 4, v);
      } else if (tid < 512) {
        const int i2 = tid - 256;                 // 0..255
        const int b = i2 >> 3, uo = (i2 & 7) * 4; // b 0..31, uo 0..28
        store8(Abf + ((size_t)(t * NB + b)) * 512 + ug + uo,   // m = t*32+b
               *(const unsigned long long*)(astage + b * 32 + uo));
      }
      __syncthreads();
      if (tid == 0)
        __hip_atomic_store(f1 + g * 16, t + 1, __ATOMIC_RELEASE,
                           __HIP_MEMORY_SCOPE_AGENT);
    }
  } else {
    // ---------------- overlapped gemm: one 128-col n-tile per block ----------------
    f16_t* AsB = (f16_t*)pool;             // [2][256*32] = 32 KB
    f16_t* BsB = (f16_t*)(pool + 32768);   // [2][128*32] = 16 KB
    const int r_in = lane >> 2;
    const int c8 = (lane & 3) * 8;

    for (int tl = bid - 24; tl < 250; tl += 232) {
      const int n0 = tl * 128;

      // Phase A: convert own W_out slab [n0, n0+128) fp32 -> f16 (replaces k_wcvt)
      for (int i = tid; i < 128 * 512 / 8; i += 768) {
        const float* src = Wout + (size_t)n0 * 512 + i * 8;
        f32x4 a = *(const f32x4*)src;
        f32x4 b = *(const f32x4*)(src + 4);
        f16x8 o;
        o[0] = (f16_t)a[0]; o[1] = (f16_t)a[1]; o[2] = (f16_t)a[2]; o[3] = (f16_t)a[3];
        o[4] = (f16_t)b[0]; o[5] = (f16_t)b[1]; o[6] = (f16_t)b[2]; o[7] = (f16_t)b[3];
        *(f16x8*)(Wf + (size_t)n0 * 512 + i * 8) = o;
      }
      __syncthreads();

      for (int mp = 0; mp < 8; ++mp) {
        const int m0 = mp * 256;            // rows m = t*32+b, t in [mp*8, mp*8+8)
        if (tid < 16) wait_flag(f1 + tid * 16, mp * 8 + 8);
        if (tid == 0) __builtin_amdgcn_fence(__ATOMIC_ACQUIRE, "agent");
        __syncthreads();

        auto stage = [&](int buf, int kk) {
          if (wave < 8) {                   // A rows: wave*32 .. +32
            const f16_t* Ag = Abf + (size_t)(m0 + wave * 32 + r_in) * NH + kk + c8;
            f16_t* la = AsB + buf * 8192 + (wave * 32) * 32;
            __builtin_amdgcn_global_load_lds((gvoid_t*)Ag, (lvoid_t*)la, 16, 0, 0);
            __builtin_amdgcn_global_load_lds((gvoid_t*)(Ag + 16 * NH),
                                             (lvoid_t*)(la + 16 * 32), 16, 0, 0);
          } else {                          // B rows: (wave-8)*32 .. +32
            const f16_t* Bg = Wf + (size_t)(n0 + (wave - 8) * 32 + r_in) * NH + kk + c8;
            f16_t* lb = BsB + buf * 4096 + ((wave - 8) * 32) * 32;
            __builtin_amdgcn_global_load_lds((gvoid_t*)Bg, (lvoid_t*)lb, 16, 0, 0);
            __builtin_amdgcn_global_load_lds((gvoid_t*)(Bg + 16 * NH),
                                             (lvoid_t*)(lb + 16 * 32), 16, 0, 0);
          }
        };

        f32x4 acc[4][4];
        #pragma unroll
        for (int i = 0; i < 4; ++i)
          #pragma unroll
          for (int j = 0; j < 4; ++j)
            acc[i][j] = (f32x4){0.f, 0.f, 0.f, 0.f};

        const int wm = (wave >> 1) * 64;
        const int wn = (wave & 1) * 64;
        const int arow = lane & 15;
        const int kg = (lane >> 4) * 8;

        stage(0, 0);
        __syncthreads();
        for (int kt = 0; kt < NH / 32; ++kt) {
          const int buf = kt & 1;
          if (kt + 1 < NH / 32) stage(buf ^ 1, (kt + 1) * 32);
          if (wave < 8) {
            f16x8 af[4], bfr[4];
            #pragma unroll
            for (int i = 0; i < 4; ++i) {
              af[i]  = *(const f16x8*)&AsB[buf * 8192 + (wm + i * 16 + arow) * 32 + kg];
              bfr[i] = *(const f16x8*)&BsB[buf * 4096 + (wn + i * 16 + arow) * 32 + kg];
            }
            #pragma unroll
            for (int i = 0; i < 4; ++i)
              #pragma unroll
              for (int j = 0; j < 4; ++j)
                acc[i][j] = __builtin_amdgcn_mfma_f32_16x16x32_f16(af[i], bfr[j],
                                                                   acc[i][j], 0, 0, 0);
          }
          __syncthreads();
        }

        if (wave < 8) {
          const int crow = (lane >> 4) * 4;
          const int ccol = lane & 15;
          #pragma unroll
          for (int j = 0; j < 4; ++j) {
            const int gcol = n0 + wn + j * 16 + ccol;
            const float bb = bout[gcol];
            #pragma unroll
            for (int i = 0; i < 4; ++i) {
              #pragma unroll
              for (int r = 0; r < 4; ++r) {
                const int am = m0 + wm + i * 16 + crow + r;      // = t*32 + b
                const int orow = (am & 31) * 64 + (am >> 5);     // = b*64 + t
                C[(size_t)orow * NV + gcol] = acc[i][j][r] + bb;
              }
            }
          }
        }
      }
    }
  }
}

// ---------------- in-place row log_softmax ----------------

__global__ __launch_bounds__(256) void k_lsm(float* __restrict__ out) {
  __shared__ f16_t row[NV];
  __shared__ float redm[4], reds[4];
  const int m = blockIdx.x;
  float* p = out + (size_t)m * NV;
  const int tid = threadIdx.x;
  float mx = -3.0e38f;
  for (int i = tid; i < NV; i += 256) {
    float x = p[i];
    row[i] = (f16_t)x;
    mx = fmaxf(mx, x);
  }
  #pragma unroll
  for (int o = 1; o < 64; o <<= 1) mx = fmaxf(mx, __shfl_xor(mx, o, 64));
  if ((tid & 63) == 0) redm[tid >> 6] = mx;
  __syncthreads();
  mx = fmaxf(fmaxf(redm[0], redm[1]), fmaxf(redm[2], redm[3]));
  float s = 0.f;
  for (int i = tid; i < NV; i += 256) s += __expf((float)row[i] - mx);
  #pragma unroll
  for (int o = 1; o < 64; o <<= 1) s += __shfl_xor(s, o, 64);
  if ((tid & 63) == 0) reds[tid >> 6] = s;
  __syncthreads();
  const float lse = mx + __logf(reds[0] + reds[1] + reds[2] + reds[3]);
  for (int i = tid; i < NV; i += 256) p[i] = (float)row[i] - lse;
}

// ws layout (bytes)
constexpr size_t WS_F0  = 0;      // 8 flags, 64B apart
constexpr size_t WS_F1  = 512;    // 16 flags, 64B apart
constexpr size_t WS_GI0 = 2048;
constexpr size_t WS_HB0 = WS_GI0 + sizeof(f16_t) * (size_t)NT * NG * NB;       // 6.29 MB
constexpr size_t WS_HB1 = WS_HB0 + sizeof(f16_t) * (size_t)(NT + 1) * NH * NB; // +2.13 MB
constexpr size_t WS_ABF = WS_HB1 + sizeof(f16_t) * (size_t)(NT + 1) * NH * NB;
constexpr size_t WS_WF  = WS_ABF + sizeof(f16_t) * (size_t)NM * NH;

}  // namespace

extern "C" void kernel_launch(void* const* d_in, const int* in_sizes, int n_in,
                              void* d_out, int out_size, void* d_ws, size_t ws_size,
                              hipStream_t stream) {
  const float* enc_h = (const float*)d_in[1];
  const int*   tgt   = (const int*)d_in[2];
  const float* emb   = (const float*)d_in[3];
  const float* Wih0  = (const float*)d_in[4];
  const float* Whh0  = (const float*)d_in[5];
  const float* bih0  = (const float*)d_in[6];
  const float* bhh0  = (const float*)d_in[7];
  const float* Wih1  = (const float*)d_in[8];
  const float* Whh1  = (const float*)d_in[9];
  const float* bih1  = (const float*)d_in[10];
  const float* bhh1  = (const float*)d_in[11];
  const float* Wout  = (const float*)d_in[12];
  const float* bout  = (const float*)d_in[13];

  char* ws = (char*)d_ws;
  int*    f0   = (int*)(ws + WS_F0);
  int*    f1   = (int*)(ws + WS_F1);
  f16_t*  Gi0  = (f16_t*)(ws + WS_GI0);
  f16_t*  hb0  = (f16_t*)(ws + WS_HB0);
  f16_t*  hb1  = (f16_t*)(ws + WS_HB1);
  f16_t*  Abf  = (f16_t*)(ws + WS_ABF);
  f16_t*  Wf   = (f16_t*)(ws + WS_WF);

  float* out  = (float*)d_out;
  float* hfin = out + (size_t)NM * NV;

  hipMemsetAsync(ws, 0, 2048, stream);
  k_hinit<<<(2 * NB * NH) / 256, 256, 0, stream>>>(enc_h, hb0, hb1);
  k_gi0<<<dim3(NG / 64, NT), 256, 0, stream>>>(tgt, emb, Wih0, bih0, Gi0);
  k_mega<<<256, 768, 0, stream>>>(Gi0, Whh0, bhh0, Wih1, bih1, Whh1, bhh1,
                                  enc_h, hb0, hb1, Abf, hfin, Wout, bout,
                                  Wf, out, f0, f1);
  k_lsm<<<NM, 256, 0, stream>>>(out);
}

// Round 10
// 934.754 us; speedup vs baseline: 1.1775x; 1.0452x over previous
//
#include <hip/hip_runtime.h>
#include <hip/hip_bf16.h>

namespace {

constexpr int NV = 32000;
constexpr int NE = 256;
constexpr int NH = 512;
constexpr int NB = 32;
constexpr int NT = 64;
constexpr int NG = 3 * NH;    // 1536
constexpr int NM = NB * NT;   // 2048
constexpr int SOS = 1;
constexpr int NTILE = 250;    // NV/128
constexpr int NITEM = 8 * NTILE;

typedef _Float16 f16_t;
typedef _Float16 f16x8 __attribute__((ext_vector_type(8)));
typedef float f32x4 __attribute__((ext_vector_type(4)));

typedef __attribute__((address_space(1))) void gvoid_t;
typedef __attribute__((address_space(3))) void lvoid_t;

// fragment-order offset of h[u][b] inside a 512x32 f16 step buffer.
// B-frag of mfma_f32_16x16x32_f16: lane l holds col n=l&15, k=(l>>4)*8+j.
__device__ __forceinline__ int fragoff(int u, int b) {
  return ((b >> 4) * 16 + (u >> 5)) * 512 +
         ((((u >> 3) & 3) * 16) + (b & 15)) * 8 + (u & 7);
}

__device__ __forceinline__ void load_wf(const float* wrow, f16x8* wf) {
  #pragma unroll
  for (int kc = 0; kc < 16; ++kc) {
    f32x4 a = *(const f32x4*)(wrow + kc * 32);
    f32x4 c = *(const f32x4*)(wrow + kc * 32 + 4);
    f16x8 w;
    w[0] = (f16_t)a[0]; w[1] = (f16_t)a[1]; w[2] = (f16_t)a[2]; w[3] = (f16_t)a[3];
    w[4] = (f16_t)c[0]; w[5] = (f16_t)c[1]; w[6] = (f16_t)c[2]; w[7] = (f16_t)c[3];
    wf[kc] = w;
  }
}

__device__ __forceinline__ float sigm(float x) { return 1.f / (1.f + __expf(-x)); }

// Per-block flag words, each on its own 64B line (int stride 16).
__device__ __forceinline__ void wait_flag(int* p, int target) {
  while (__hip_atomic_load(p, __ATOMIC_RELAXED, __HIP_MEMORY_SCOPE_AGENT) < target)
    __builtin_amdgcn_s_sleep(1);
}

// Write-through 8B store (relaxed agent atomic): data visible at coherent point.
__device__ __forceinline__ void store8(void* dst, unsigned long long v) {
  __hip_atomic_store((unsigned long long*)dst, v, __ATOMIC_RELAXED,
                     __HIP_MEMORY_SCOPE_AGENT);
}

// ---------------- prologue kernels ----------------

__global__ __launch_bounds__(256) void k_hinit(const float* __restrict__ eh,
                                               f16_t* __restrict__ hb0,
                                               f16_t* __restrict__ hb1) {
  int idx = blockIdx.x * 256 + threadIdx.x;   // l*16384 + b*512 + u
  int u = idx & 511;
  int b = (idx >> 9) & 31;
  int l = idx >> 14;
  f16_t v = (f16_t)eh[idx];
  (l ? hb1 : hb0)[fragoff(u, b)] = v;
}

// R10: coalesced emb staging (256 lanes load one 1KB row per iter) + stride-33
// LDS padding so both the staging store and the dot-product read are
// bank-conflict-free (the R9 version scalar-gathered at 128B stride).
__global__ __launch_bounds__(256) void k_gi0(const int* __restrict__ tgt,
                                             const float* __restrict__ emb,
                                             const float* __restrict__ Wih0,
                                             const float* __restrict__ bih0,
                                             f16_t* __restrict__ Gi0) {
  __shared__ float xs[NE * 33];   // [e][b] stride 33, 33.8 KB
  __shared__ int toks[NB];
  const int t = blockIdx.y;
  const int tid = threadIdx.x;
  if (tid < NB) toks[tid] = (t == 0) ? SOS : tgt[tid * NT + (t - 1)];
  __syncthreads();
  #pragma unroll 4
  for (int b = 0; b < NB; ++b) {
    float v = emb[(size_t)toks[b] * NE + tid];
    xs[tid * 33 + b] = v > 0.f ? v : 0.f;
  }
  __syncthreads();
  const int b = tid & 31;
  #pragma unroll
  for (int jj = 0; jj < 8; ++jj) {
    const int j = blockIdx.x * 64 + jj * 8 + (tid >> 5);
    float acc = bih0[j];
    const f32x4* wr = (const f32x4*)(Wih0 + (size_t)j * NE);
    #pragma unroll 4
    for (int e4 = 0; e4 < NE / 4; ++e4) {
      f32x4 w = wr[e4];
      acc += w[0] * xs[(4 * e4 + 0) * 33 + b] + w[1] * xs[(4 * e4 + 1) * 33 + b]
           + w[2] * xs[(4 * e4 + 2) * 33 + b] + w[3] * xs[(4 * e4 + 3) * 33 + b];
    }
    Gi0[((size_t)t * NG + j) * NB + b] = (f16_t)acc;
  }
}

// ---------------- mega kernel: persistent rnn + overlapped gemm ----------------
// grid = 256 x 768 (1 block/CU, co-resident). blocks 0..7: layer 0; 8..23:
// layer 1 (R7-proven). blocks 24..255: 2000 (mp,tile) gemm items, statically
// interleaved by readiness level mp -> the mp=7 wave (ready at t=64) is spread
// over 232 blocks, collapsing R9's 2-tile ~180us tail to ~1 panel.

__global__ __launch_bounds__(768) void k_mega(
    const f16_t* __restrict__ Gi0,
    const float* __restrict__ Whh0, const float* __restrict__ bhh0,
    const float* __restrict__ Wih1, const float* __restrict__ bih1,
    const float* __restrict__ Whh1, const float* __restrict__ bhh1,
    const float* __restrict__ eh,
    f16_t* __restrict__ hb0, f16_t* __restrict__ hb1,
    f16_t* __restrict__ Abf, float* __restrict__ hfin,
    const float* __restrict__ Wout, const float* __restrict__ bout,
    f16_t* __restrict__ Wf, float* __restrict__ C,
    int* f0, int* f1, int* wflag) {
  __shared__ __align__(16) char pool[49152];   // rnn: 30KB | gemm: 48KB
  const int tid = threadIdx.x;
  const int wave = tid >> 6, lane = tid & 63;
  const int bid = blockIdx.x;
  const int eb = tid & 31, eu0 = (tid >> 5) & 15;

  if (bid < 8) {
    // ---------------- layer 0 (R7 verbatim) ----------------
    float* gLDS = (float*)pool;                       // 24 KB
    f16_t* hstage = (f16_t*)(pool + 24576);           // 4 KB
    const int ug = bid * 64;
    const int gate = wave >> 2, tile = wave & 3;
    const int row = gate * 512 + ug + tile * 16 + (lane & 15);
    f16x8 wf[16];
    load_wf(Whh0 + (size_t)row * NH + (lane >> 4) * 8, wf);

    float hprev[4], br[4], bz[4], bn[4];
    if (tid < 512) {
      #pragma unroll
      for (int i = 0; i < 4; ++i) {
        int u = ug + eu0 + i * 16;
        hprev[i] = eh[eb * NH + u];
        br[i] = bhh0[u]; bz[i] = bhh0[512 + u]; bn[i] = bhh0[1024 + u];
      }
    }

    for (int t = 0; t < NT; ++t) {
      float gr[4], gz[4], gn[4];
      if (tid < 512) {                       // prefetch gi (overlaps the wait)
        const f16_t* g = Gi0 + (size_t)t * NG * NB;
        #pragma unroll
        for (int i = 0; i < 4; ++i) {
          int u = ug + eu0 + i * 16;
          gr[i] = (float)g[u * NB + eb];
          gz[i] = (float)g[(512 + u) * NB + eb];
          gn[i] = (float)g[(1024 + u) * NB + eb];
        }
      }
      if (t > 0) {
        if (tid < 8) wait_flag(f0 + tid * 16, t);
        if (tid == 0) __builtin_amdgcn_fence(__ATOMIC_ACQUIRE, "agent");
      }
      __syncthreads();
      const f16_t* hb = hb0 + (size_t)t * 16384;
      f32x4 acc0 = {0.f, 0.f, 0.f, 0.f}, acc1 = {0.f, 0.f, 0.f, 0.f};
      #pragma unroll
      for (int kc = 0; kc < 16; ++kc) {
        f16x8 b0 = *(const f16x8*)(hb + kc * 512 + lane * 8);
        f16x8 b1 = *(const f16x8*)(hb + (16 + kc) * 512 + lane * 8);
        acc0 = __builtin_amdgcn_mfma_f32_16x16x32_f16(wf[kc], b0, acc0, 0, 0, 0);
        acc1 = __builtin_amdgcn_mfma_f32_16x16x32_f16(wf[kc], b1, acc1, 0, 0, 0);
      }
      {
        const int m0 = (lane >> 4) * 4, col = lane & 15;
        #pragma unroll
        for (int r = 0; r < 4; ++r) {
          int ul = tile * 16 + m0 + r;
          gLDS[(gate * 64 + ul) * 32 + col] = acc0[r];
          gLDS[(gate * 64 + ul) * 32 + 16 + col] = acc1[r];
        }
      }
      __syncthreads();
      if (tid < 512) {
        #pragma unroll
        for (int i = 0; i < 4; ++i) {
          int ul = eu0 + i * 16;
          float rt = gLDS[(0 * 64 + ul) * 32 + eb];
          float zt = gLDS[(1 * 64 + ul) * 32 + eb];
          float nt_ = gLDS[(2 * 64 + ul) * 32 + eb];
          float r = sigm(gr[i] + rt + br[i]);
          float z = sigm(gz[i] + zt + bz[i]);
          float n = tanhf(gn[i] + r * (nt_ + bn[i]));
          float hnew = (1.f - z) * n + z * hprev[i];
          hprev[i] = hnew;
          hstage[((eb >> 4) * 2 + (ul >> 5)) * 512 +
                 ((((ul >> 3) & 3) * 16) + (eb & 15)) * 8 + (ul & 7)] = (f16_t)hnew;
          if (t == NT - 1) hfin[eb * NH + ug + ul] = hnew;
        }
      }
      __syncthreads();
      if (tid < 512) {
        const int chunk = tid >> 7, w = tid & 127;
        const unsigned long long v =
            *(const unsigned long long*)(hstage + chunk * 512 + w * 4);
        store8(hb0 + (size_t)(t + 1) * 16384 +
               ((chunk >> 1) * 16 + (ug >> 5) + (chunk & 1)) * 512 + w * 4, v);
      }
      __syncthreads();
      if (tid == 0)
        __hip_atomic_store(f0 + bid * 16, t + 1, __ATOMIC_RELEASE,
                           __HIP_MEMORY_SCOPE_AGENT);
    }
  } else if (bid < 24) {
    // ---------------- layer 1 (R7 verbatim, Abf row = t*32+b) ----------------
    float* gLDS = (float*)pool;
    f16_t* hstage = (f16_t*)(pool + 24576);
    f16_t* astage = (f16_t*)(pool + 28672);
    const int g = bid - 8, ug = g * 32;
    const int mm = wave >= 6;                 // 0: Wih1 (x=h0), 1: Whh1 (h1)
    const int w6 = mm ? wave - 6 : wave;
    const int gate = w6 >> 1, tile = w6 & 1;
    const int row = gate * 512 + ug + tile * 16 + (lane & 15);
    const float* W = mm ? Whh1 : Wih1;
    f16x8 wf[16];
    load_wf(W + (size_t)row * NH + (lane >> 4) * 8, wf);

    float hprev[2], bir[2], biz[2], bin_[2], bhr[2], bhz[2], bhn[2];
    if (tid < 512) {
      #pragma unroll
      for (int i = 0; i < 2; ++i) {
        int u = ug + eu0 + i * 16;
        hprev[i] = eh[16384 + eb * NH + u];
        bir[i] = bih1[u]; biz[i] = bih1[512 + u]; bin_[i] = bih1[1024 + u];
        bhr[i] = bhh1[u]; bhz[i] = bhh1[512 + u]; bhn[i] = bhh1[1024 + u];
      }
    }

    for (int t = 0; t < NT; ++t) {
      if (tid < 24) {                        // parallel poll: 8x f0, 16x f1
        int* p   = (tid < 8) ? (f0 + tid * 16) : (f1 + (tid - 8) * 16);
        int tgt  = (tid < 8) ? (t + 1) : t;
        wait_flag(p, tgt);
      }
      if (tid == 0) __builtin_amdgcn_fence(__ATOMIC_ACQUIRE, "agent");
      __syncthreads();
      const f16_t* hb = mm ? (hb1 + (size_t)t * 16384)
                           : (hb0 + (size_t)(t + 1) * 16384);
      f32x4 acc0 = {0.f, 0.f, 0.f, 0.f}, acc1 = {0.f, 0.f, 0.f, 0.f};
      #pragma unroll
      for (int kc = 0; kc < 16; ++kc) {
        f16x8 b0 = *(const f16x8*)(hb + kc * 512 + lane * 8);
        f16x8 b1 = *(const f16x8*)(hb + (16 + kc) * 512 + lane * 8);
        acc0 = __builtin_amdgcn_mfma_f32_16x16x32_f16(wf[kc], b0, acc0, 0, 0, 0);
        acc1 = __builtin_amdgcn_mfma_f32_16x16x32_f16(wf[kc], b1, acc1, 0, 0, 0);
      }
      {
        const int m0 = (lane >> 4) * 4, col = lane & 15;
        #pragma unroll
        for (int r = 0; r < 4; ++r) {
          int ul = tile * 16 + m0 + r;
          gLDS[((mm * 3 + gate) * 32 + ul) * 32 + col] = acc0[r];
          gLDS[((mm * 3 + gate) * 32 + ul) * 32 + 16 + col] = acc1[r];
        }
      }
      __syncthreads();
      if (tid < 512) {
        #pragma unroll
        for (int i = 0; i < 2; ++i) {
          int ul = eu0 + i * 16;
          float ir  = gLDS[((0 * 3 + 0) * 32 + ul) * 32 + eb] + bir[i];
          float iz  = gLDS[((0 * 3 + 1) * 32 + ul) * 32 + eb] + biz[i];
          float in_ = gLDS[((0 * 3 + 2) * 32 + ul) * 32 + eb] + bin_[i];
          float hr  = gLDS[((1 * 3 + 0) * 32 + ul) * 32 + eb] + bhr[i];
          float hz  = gLDS[((1 * 3 + 1) * 32 + ul) * 32 + eb] + bhz[i];
          float hn  = gLDS[((1 * 3 + 2) * 32 + ul) * 32 + eb] + bhn[i];
          float r = sigm(ir + hr);
          float z = sigm(iz + hz);
          float n = tanhf(in_ + r * hn);
          float hnew = (1.f - z) * n + z * hprev[i];
          hprev[i] = hnew;
          f16_t hv = (f16_t)hnew;
          hstage[(eb >> 4) * 512 +
                 ((((ul >> 3) & 3) * 16) + (eb & 15)) * 8 + (ul & 7)] = hv;
          astage[eb * 32 + ul] = hv;
          if (t == NT - 1) hfin[16384 + eb * NH + ug + ul] = hnew;
        }
      }
      __syncthreads();
      if (tid < 256) {
        const int chunk = tid >> 7, w = tid & 127;
        const unsigned long long v =
            *(const unsigned long long*)(hstage + chunk * 512 + w * 4);
        store8(hb1 + (size_t)(t + 1) * 16384 + (chunk * 16 + g) * 512 + w * 4, v);
      } else if (tid < 512) {
        const int i2 = tid - 256;                 // 0..255
        const int b = i2 >> 3, uo = (i2 & 7) * 4; // b 0..31, uo 0..28
        store8(Abf + ((size_t)(t * NB + b)) * 512 + ug + uo,   // m = t*32+b
               *(const unsigned long long*)(astage + b * 32 + uo));
      }
      __syncthreads();
      if (tid == 0)
        __hip_atomic_store(f1 + g * 16, t + 1, __ATOMIC_RELEASE,
                           __HIP_MEMORY_SCOPE_AGENT);
    }
  } else {
    // ---------------- gemm workers: 2000 static (mp, tile) items ----------------
    f16_t* AsB = (f16_t*)pool;             // [2][256*32] = 32 KB
    f16_t* BsB = (f16_t*)(pool + 32768);   // [2][128*32] = 16 KB
    const int r_in = lane >> 2;
    const int c8 = (lane & 3) * 8;

    // Phase A: convert assigned W_out slabs fp32 -> f16, publish per-slab flag.
    for (int tl = bid - 24; tl < NTILE; tl += 232) {
      for (int i = tid; i < 128 * 512 / 8; i += 768) {
        const float* src = Wout + (size_t)tl * 128 * 512 + i * 8;
        f32x4 a = *(const f32x4*)src;
        f32x4 b = *(const f32x4*)(src + 4);
        f16x8 o;
        o[0] = (f16_t)a[0]; o[1] = (f16_t)a[1]; o[2] = (f16_t)a[2]; o[3] = (f16_t)a[3];
        o[4] = (f16_t)b[0]; o[5] = (f16_t)b[1]; o[6] = (f16_t)b[2]; o[7] = (f16_t)b[3];
        *(f16x8*)(Wf + (size_t)tl * 128 * 512 + i * 8) = o;
      }
      __syncthreads();
      if (tid == 0)
        __hip_atomic_store(wflag + tl * 16, 1, __ATOMIC_RELEASE,
                           __HIP_MEMORY_SCOPE_AGENT);
    }

    // Phase B: items ordered by readiness level mp = item/250.
    for (int item = bid - 24; item < NITEM; item += 232) {
      const int mp = item / NTILE, tl = item - mp * NTILE;
      const int m0 = mp * 256;             // rows m = t*32+b, t in [mp*8, mp*8+8)
      const int n0 = tl * 128;
      if (tid < 16) wait_flag(f1 + tid * 16, mp * 8 + 8);
      else if (tid == 16) wait_flag(wflag + tl * 16, 1);
      if (tid == 0) __builtin_amdgcn_fence(__ATOMIC_ACQUIRE, "agent");
      __syncthreads();

      auto stage = [&](int buf, int kk) {
        if (wave < 8) {                   // A rows: wave*32 .. +32
          const f16_t* Ag = Abf + (size_t)(m0 + wave * 32 + r_in) * NH + kk + c8;
          f16_t* la = AsB + buf * 8192 + (wave * 32) * 32;
          __builtin_amdgcn_global_load_lds((gvoid_t*)Ag, (lvoid_t*)la, 16, 0, 0);
          __builtin_amdgcn_global_load_lds((gvoid_t*)(Ag + 16 * NH),
                                           (lvoid_t*)(la + 16 * 32), 16, 0, 0);
        } else {                          // B rows: (wave-8)*32 .. +32
          const f16_t* Bg = Wf + (size_t)(n0 + (wave - 8) * 32 + r_in) * NH + kk + c8;
          f16_t* lb = BsB + buf * 4096 + ((wave - 8) * 32) * 32;
          __builtin_amdgcn_global_load_lds((gvoid_t*)Bg, (lvoid_t*)lb, 16, 0, 0);
          __builtin_amdgcn_global_load_lds((gvoid_t*)(Bg + 16 * NH),
                                           (lvoid_t*)(lb + 16 * 32), 16, 0, 0);
        }
      };

      f32x4 acc[4][4];
      #pragma unroll
      for (int i = 0; i < 4; ++i)
        #pragma unroll
        for (int j = 0; j < 4; ++j)
          acc[i][j] = (f32x4){0.f, 0.f, 0.f, 0.f};

      const int wm = (wave >> 1) * 64;
      const int wn = (wave & 1) * 64;
      const int arow = lane & 15;
      const int kg = (lane >> 4) * 8;

      stage(0, 0);
      __syncthreads();
      for (int kt = 0; kt < NH / 32; ++kt) {
        const int buf = kt & 1;
        if (kt + 1 < NH / 32) stage(buf ^ 1, (kt + 1) * 32);
        if (wave < 8) {
          f16x8 af[4], bfr[4];
          #pragma unroll
          for (int i = 0; i < 4; ++i) {
            af[i]  = *(const f16x8*)&AsB[buf * 8192 + (wm + i * 16 + arow) * 32 + kg];
            bfr[i] = *(const f16x8*)&BsB[buf * 4096 + (wn + i * 16 + arow) * 32 + kg];
          }
          #pragma unroll
          for (int i = 0; i < 4; ++i)
            #pragma unroll
            for (int j = 0; j < 4; ++j)
              acc[i][j] = __builtin_amdgcn_mfma_f32_16x16x32_f16(af[i], bfr[j],
                                                                 acc[i][j], 0, 0, 0);
        }
        __syncthreads();
      }

      if (wave < 8) {
        const int crow = (lane >> 4) * 4;
        const int ccol = lane & 15;
        #pragma unroll
        for (int j = 0; j < 4; ++j) {
          const int gcol = n0 + wn + j * 16 + ccol;
          const float bb = bout[gcol];
          #pragma unroll
          for (int i = 0; i < 4; ++i) {
            #pragma unroll
            for (int r = 0; r < 4; ++r) {
              const int am = m0 + wm + i * 16 + crow + r;      // = t*32 + b
              const int orow = (am & 31) * 64 + (am >> 5);     // = b*64 + t
              C[(size_t)orow * NV + gcol] = acc[i][j][r] + bb;
            }
          }
        }
      }
    }
  }
}

// ---------------- in-place row log_softmax ----------------

__global__ __launch_bounds__(256) void k_lsm(float* __restrict__ out) {
  __shared__ f16_t row[NV];
  __shared__ float redm[4], reds[4];
  const int m = blockIdx.x;
  float* p = out + (size_t)m * NV;
  const int tid = threadIdx.x;
  float mx = -3.0e38f;
  for (int i = tid; i < NV; i += 256) {
    float x = p[i];
    row[i] = (f16_t)x;
    mx = fmaxf(mx, x);
  }
  #pragma unroll
  for (int o = 1; o < 64; o <<= 1) mx = fmaxf(mx, __shfl_xor(mx, o, 64));
  if ((tid & 63) == 0) redm[tid >> 6] = mx;
  __syncthreads();
  mx = fmaxf(fmaxf(redm[0], redm[1]), fmaxf(redm[2], redm[3]));
  float s = 0.f;
  for (int i = tid; i < NV; i += 256) s += __expf((float)row[i] - mx);
  #pragma unroll
  for (int o = 1; o < 64; o <<= 1) s += __shfl_xor(s, o, 64);
  if ((tid & 63) == 0) reds[tid >> 6] = s;
  __syncthreads();
  const float lse = mx + __logf(reds[0] + reds[1] + reds[2] + reds[3]);
  for (int i = tid; i < NV; i += 256) p[i] = (float)row[i] - lse;
}

// ws layout (bytes)
constexpr size_t WS_F0  = 0;      // 8 flags, 64B apart
constexpr size_t WS_F1  = 512;    // 16 flags, 64B apart
constexpr size_t WS_WFL = 2048;   // 250 W-slab flags, 64B apart (16000 B)
constexpr size_t WS_GI0 = 18432;
constexpr size_t WS_HB0 = WS_GI0 + sizeof(f16_t) * (size_t)NT * NG * NB;       // 6.29 MB
constexpr size_t WS_HB1 = WS_HB0 + sizeof(f16_t) * (size_t)(NT + 1) * NH * NB; // +2.13 MB
constexpr size_t WS_ABF = WS_HB1 + sizeof(f16_t) * (size_t)(NT + 1) * NH * NB;
constexpr size_t WS_WF  = WS_ABF + sizeof(f16_t) * (size_t)NM * NH;

}  // namespace

extern "C" void kernel_launch(void* const* d_in, const int* in_sizes, int n_in,
                              void* d_out, int out_size, void* d_ws, size_t ws_size,
                              hipStream_t stream) {
  const float* enc_h = (const float*)d_in[1];
  const int*   tgt   = (const int*)d_in[2];
  const float* emb   = (const float*)d_in[3];
  const float* Wih0  = (const float*)d_in[4];
  const float* Whh0  = (const float*)d_in[5];
  const float* bih0  = (const float*)d_in[6];
  const float* bhh0  = (const float*)d_in[7];
  const float* Wih1  = (const float*)d_in[8];
  const float* Whh1  = (const float*)d_in[9];
  const float* bih1  = (const float*)d_in[10];
  const float* bhh1  = (const float*)d_in[11];
  const float* Wout  = (const float*)d_in[12];
  const float* bout  = (const float*)d_in[13];

  char* ws = (char*)d_ws;
  int*    f0   = (int*)(ws + WS_F0);
  int*    f1   = (int*)(ws + WS_F1);
  int*    wfl  = (int*)(ws + WS_WFL);
  f16_t*  Gi0  = (f16_t*)(ws + WS_GI0);
  f16_t*  hb0  = (f16_t*)(ws + WS_HB0);
  f16_t*  hb1  = (f16_t*)(ws + WS_HB1);
  f16_t*  Abf  = (f16_t*)(ws + WS_ABF);
  f16_t*  Wf   = (f16_t*)(ws + WS_WF);

  float* out  = (float*)d_out;
  float* hfin = out + (size_t)NM * NV;

  hipMemsetAsync(ws, 0, 18432, stream);
  k_hinit<<<(2 * NB * NH) / 256, 256, 0, stream>>>(enc_h, hb0, hb1);
  k_gi0<<<dim3(NG / 64, NT), 256, 0, stream>>>(tgt, emb, Wih0, bih0, Gi0);
  k_mega<<<256, 768, 0, stream>>>(Gi0, Whh0, bhh0, Wih1, bih1, Whh1, bhh1,
                                  enc_h, hb0, hb1, Abf, hfin, Wout, bout,
                                  Wf, out, f0, f1, wfl);
  k_lsm<<<NM, 256, 0, stream>>>(out);
}